// Round 1
// baseline (2799.308 us; speedup 1.0000x reference)
//
#include <hip/hip_runtime.h>
#include <math.h>

#define Bc 8
#define Lc 96
#define Hc 8
#define Ec 64
#define EHc 128
#define Rr 8   // rows (b,h pairs) per block

// Block: 256 threads = 8 local rows x 32 lane-columns.
// LDS: W1 (32KB) + W2 (32KB) + ARG (2KB) + H (4KB) = 70KB -> 2 blocks/CU.
// Each thread owns 2 state elements (e0, e0+1) of its row; k1/k2/k3/y/y0 in regs.
__global__ __launch_bounds__(256, 2)
void ode_traj_kernel(const float* __restrict__ x, const float* __restrict__ ts,
                     const float* __restrict__ W1, const float* __restrict__ b1,
                     const float* __restrict__ W2, const float* __restrict__ b2,
                     float* __restrict__ out)
{
    __shared__ float W1s[Ec * EHc];   // [k][n] 64x128
    __shared__ float W2s[EHc * Ec];   // [k][n] 128x64
    __shared__ float ARGs[Rr * Ec];   // argument to f, [r][e]
    __shared__ float Hs[Rr * EHc];    // hidden activations, [r][n]

    const int tid = threadIdx.x;
    const int idx = blockIdx.x >> 3;   // trajectory index 0..95
    const int rg  = blockIdx.x & 7;    // row group 0..7

    // Stage weights to LDS (coalesced float4).
    {
        const float4* W1v = (const float4*)W1;
        const float4* W2v = (const float4*)W2;
        float4* W1sv = (float4*)W1s;
        float4* W2sv = (float4*)W2s;
#pragma unroll
        for (int i = 0; i < (Ec * EHc / 4) / 256; ++i) {
            W1sv[tid + i * 256] = W1v[tid + i * 256];
            W2sv[tid + i * 256] = W2v[tid + i * 256];
        }
    }

    const int r  = tid >> 5;          // local row 0..7
    const int tc = tid & 31;          // lane column 0..31
    const int grow = rg * Rr + r;     // global row 0..63  (= b*8 + h)
    const int bb = grow >> 3;
    const int hh = grow & 7;
    const int e0 = tc * 2;            // this thread's 2 state elements

    const float4 b1r = ((const float4*)b1)[tc];   // b1[4tc..4tc+3]
    const float2 b2r = ((const float2*)b2)[tc];   // b2[2tc..2tc+1]

    const float* xrow = x + ((bb * Lc + idx) * Hc + hh) * Ec;
    const float2 y0 = *(const float2*)(xrow + e0);
    float2 y = y0;

    float2* argp = (float2*)(ARGs + r * Ec) + tc;
    *argp = y;

    // out flat index = ((((b*L+idx)*L + j)*H + h)*E + e)*2
    float* outbase = out + ((bb * Lc + idx) * Lc * Hc + hh) * (2 * Ec);
    const int jstride = Hc * 2 * Ec;  // 1024 floats per j

    // j = idx: state is the initial condition.
    {
        float4 o; o.x = y0.x; o.y = y.x; o.z = y0.y; o.w = y.y;
        *(float4*)(outbase + idx * jstride + e0 * 2) = o;
    }
    __syncthreads();

    const float* arow = ARGs + r * Ec;
    float* hrow = Hs + r * EHc;
    const float4* w1p = ((const float4*)W1s) + tc;   // + k*32 per k-row
    const float2* w2p = ((const float2*)W2s) + tc;   // + k*32 per k-row

    // f(ARGs) for this thread's (row, 2 cols). Requires ARGs valid + synced on
    // entry. Contains one internal barrier (H handoff). Caller must barrier
    // after writing ARGs before the next call.
    auto evalf = [&]() -> float2 {
        float4 acc = b1r;
#pragma unroll 8
        for (int k = 0; k < Ec; ++k) {
            const float av = arow[k];                 // broadcast (2-way, free)
            const float4 w = w1p[k * (EHc / 4)];      // ds_read_b128
            acc.x = fmaf(av, w.x, acc.x);
            acc.y = fmaf(av, w.y, acc.y);
            acc.z = fmaf(av, w.z, acc.z);
            acc.w = fmaf(av, w.w, acc.w);
        }
        float4 th;
        th.x = tanhf(acc.x); th.y = tanhf(acc.y);
        th.z = tanhf(acc.z); th.w = tanhf(acc.w);
        ((float4*)hrow)[tc] = th;
        __syncthreads();
        float2 acc2 = b2r;
#pragma unroll 8
        for (int k = 0; k < EHc; ++k) {
            const float hv = hrow[k];                 // broadcast (2-way, free)
            const float2 w = w2p[k * (Ec / 2)];       // ds_read_b64
            acc2.x = fmaf(hv, w.x, acc2.x);
            acc2.y = fmaf(hv, w.y, acc2.y);
        }
        return acc2;
    };

    // One 3/8-rule RK4 step from current y over dt; writes output row j.
    // Invariant: ARGs holds y (synced) at entry; same at exit.
    auto rk4_out = [&](float dt, int j) {
        const float2 k1 = evalf();
        {
            const float c = dt * (1.0f / 3.0f);
            float2 a; a.x = fmaf(c, k1.x, y.x); a.y = fmaf(c, k1.y, y.y);
            *argp = a;
        }
        __syncthreads();
        const float2 k2 = evalf();
        {
            float2 a;
            a.x = y.x + dt * (k2.x - (1.0f / 3.0f) * k1.x);
            a.y = y.y + dt * (k2.y - (1.0f / 3.0f) * k1.y);
            *argp = a;
        }
        __syncthreads();
        const float2 k3 = evalf();
        {
            float2 a;
            a.x = y.x + dt * (k1.x - k2.x + k3.x);
            a.y = y.y + dt * (k1.y - k2.y + k3.y);
            *argp = a;
        }
        __syncthreads();
        const float2 k4 = evalf();
        y.x += dt * (k1.x + 3.0f * (k2.x + k3.x) + k4.x) * 0.125f;
        y.y += dt * (k1.y + 3.0f * (k2.y + k3.y) + k4.y) * 0.125f;
        *argp = y;
        float4 o; o.x = y0.x; o.y = y.x; o.z = y0.y; o.w = y.y;
        *(float4*)(outbase + j * jstride + e0 * 2) = o;
        __syncthreads();
    };

    // Forward: t_s -> t_{s+1} for s = idx .. L-2, emit at j = s+1.
    for (int s = idx; s < Lc - 1; ++s) {
        rk4_out(ts[s + 1] - ts[s], s + 1);
    }

    // Reset to initial state for the backward sweep.
    y = y0;
    *argp = y;
    __syncthreads();

    // Backward: t_s -> t_{s-1} for s = idx .. 1, emit at j = s-1 (dt < 0).
    for (int s = idx; s >= 1; --s) {
        rk4_out(ts[s - 1] - ts[s], s - 1);
    }
}

extern "C" void kernel_launch(void* const* d_in, const int* in_sizes, int n_in,
                              void* d_out, int out_size, void* d_ws, size_t ws_size,
                              hipStream_t stream) {
    const float* x  = (const float*)d_in[0];
    const float* ts = (const float*)d_in[1];
    const float* W1 = (const float*)d_in[2];
    const float* b1 = (const float*)d_in[3];
    const float* W2 = (const float*)d_in[4];
    const float* b2 = (const float*)d_in[5];
    float* out = (float*)d_out;

    dim3 grid(Lc * (64 / Rr));  // 96 trajectories x 8 row-groups = 768 blocks
    dim3 block(256);
    ode_traj_kernel<<<grid, block, 0, stream>>>(x, ts, W1, b1, W2, b2, out);
}

// Round 2
// 2736.032 us; speedup vs baseline: 1.0231x; 1.0231x over previous
//
#include <hip/hip_runtime.h>

#define Lc 96
#define Hc 8
#define Ec 64
#define EHc 128
#define ROWS 24     // row-slots per block; 6144 rows / 24 = 256 blocks exactly
#define AP 25       // A_T pitch (pad to break bank stride)
#define HP 25       // H_T pitch

// tanh(x) = 1 - 2/(e^{2x}+1); v_exp_f32 + v_rcp_f32, ~1e-7 abs err.
__device__ __forceinline__ float fast_tanh(float x) {
    const float e = __builtin_amdgcn_exp2f(x * 2.8853900817779268f); // 2*log2(e)
    return 1.0f - 2.0f * __builtin_amdgcn_rcpf(e + 1.0f);
}

// 256 threads = 8 row-groups (rg) x 32 col-lanes (c).
// Thread owns 3 rows (3*rg..3*rg+2); L1 tile 3x4 (cols 4c..4c+3 of EH),
// L2 tile 3x2 (cols 2c..2c+1 of E) == its 6 state elements.
// LDS: W1 32K + W2 32K + A_T 6.4K + H_T 12.8K + ts = ~84KB -> 1 block/CU.
__global__ __launch_bounds__(256, 1)
void ode_traj_kernel(const float* __restrict__ x, const float* __restrict__ ts,
                     const float* __restrict__ W1, const float* __restrict__ b1,
                     const float* __restrict__ W2, const float* __restrict__ b2,
                     float* __restrict__ out)
{
    __shared__ float W1s[Ec * EHc];   // [k][n] 64x128
    __shared__ float W2s[EHc * Ec];   // [k][n] 128x64
    __shared__ float As[Ec * AP];     // argument, transposed [e][row]
    __shared__ float Hs[EHc * HP];    // hidden, transposed [n][row]
    __shared__ float tss[Lc];

    const int tid = threadIdx.x;

    // Stage weights (coalesced float4; 64KB total).
    {
        const float4* W1v = (const float4*)W1;
        const float4* W2v = (const float4*)W2;
        float4* W1sv = (float4*)W1s;
        float4* W2sv = (float4*)W2s;
#pragma unroll
        for (int i = 0; i < 8; ++i) {
            W1sv[tid + i * 256] = W1v[tid + i * 256];
            W2sv[tid + i * 256] = W2v[tid + i * 256];
        }
    }
    if (tid < Lc) tss[tid] = ts[tid];

    const int rg = tid >> 5;   // 0..7
    const int c  = tid & 31;   // 0..31

    int    t_[3], fs_[3], jj[3];
    long   ob_[3];
    float  dt_[3];
    float2 y0_[3], y_[3];

#pragma unroll
    for (int i = 0; i < 3; ++i) {
        const int rgl = blockIdx.x * ROWS + 3 * rg + i;  // global row-slot
        const int t  = rgl >> 6;        // trajectory index 0..95
        const int br = rgl & 63;        // row within trajectory (b*8+h)
        const int bb = br >> 3;
        const int hh = br & 7;
        t_[i]  = t;
        fs_[i] = (Lc - 1) - t;          // forward step count
        const float2 y0 = *(const float2*)(x + (((bb * Lc + t) * Hc + hh) << 6) + 2 * c);
        y0_[i] = y0;
        y_[i]  = y0;
        ob_[i] = (long)((bb * Lc + t) * Lc * Hc + hh) * (Ec * 2) + 4 * c;
        // j = t: output pair is (y0, y0)
        float4 o; o.x = y0.x; o.y = y0.x; o.z = y0.y; o.w = y0.y;
        *(float4*)(out + ob_[i] + (long)t * (Hc * Ec * 2)) = o;
        // initial argument
        As[(2 * c) * AP + 3 * rg + i]     = y0.x;
        As[(2 * c + 1) * AP + 3 * rg + i] = y0.y;
    }
    __syncthreads();

    const float4 b1r = ((const float4*)b1)[c];
    const float2 b2r = ((const float2*)b2)[c];
    const float* ap0 = As + 3 * rg;
    const float* hp0 = Hs + 3 * rg;
    const float4* w1p = ((const float4*)W1s) + c;   // + k*32 per k
    const float2* w2p = ((const float2*)W2s) + c;   // + k*32 per k

    // f(As) -> kk[i] (this thread's 3 rows x 2 cols). Entry: As valid+synced.
    // One internal barrier (H handoff). Caller must barrier after next As write.
    auto evalf = [&](float2* kk) {
        float4 acc0 = b1r, acc1 = b1r, acc2 = b1r;
#pragma unroll 8
        for (int k = 0; k < Ec; ++k) {
            const float* ap = ap0 + k * AP;           // b96 broadcast (2 addrs/wave)
            const float a0 = ap[0], a1 = ap[1], a2 = ap[2];
            const float4 w = w1p[k * (EHc / 4)];      // b128, 512B unique/wave
            acc0.x = fmaf(a0, w.x, acc0.x); acc0.y = fmaf(a0, w.y, acc0.y);
            acc0.z = fmaf(a0, w.z, acc0.z); acc0.w = fmaf(a0, w.w, acc0.w);
            acc1.x = fmaf(a1, w.x, acc1.x); acc1.y = fmaf(a1, w.y, acc1.y);
            acc1.z = fmaf(a1, w.z, acc1.z); acc1.w = fmaf(a1, w.w, acc1.w);
            acc2.x = fmaf(a2, w.x, acc2.x); acc2.y = fmaf(a2, w.y, acc2.y);
            acc2.z = fmaf(a2, w.z, acc2.z); acc2.w = fmaf(a2, w.w, acc2.w);
        }
        const float* a0f = (const float*)&acc0;
        const float* a1f = (const float*)&acc1;
        const float* a2f = (const float*)&acc2;
#pragma unroll
        for (int j = 0; j < 4; ++j) {
            float* hp = Hs + (4 * c + j) * HP + 3 * rg;
            hp[0] = fast_tanh(a0f[j]);
            hp[1] = fast_tanh(a1f[j]);
            hp[2] = fast_tanh(a2f[j]);
        }
        __syncthreads();
        float2 s0 = b2r, s1 = b2r, s2 = b2r;
#pragma unroll 8
        for (int k = 0; k < EHc; ++k) {
            const float* hp = hp0 + k * HP;           // b96 broadcast
            const float h0 = hp[0], h1 = hp[1], h2 = hp[2];
            const float2 w = w2p[k * (Ec / 2)];       // b64, 256B unique/wave
            s0.x = fmaf(h0, w.x, s0.x); s0.y = fmaf(h0, w.y, s0.y);
            s1.x = fmaf(h1, w.x, s1.x); s1.y = fmaf(h1, w.y, s1.y);
            s2.x = fmaf(h2, w.x, s2.x); s2.y = fmaf(h2, w.y, s2.y);
        }
        kk[0] = s0; kk[1] = s1; kk[2] = s2;
    };

    auto putArg = [&](const float2* na) {
#pragma unroll
        for (int i = 0; i < 3; ++i) {
            As[(2 * c) * AP + 3 * rg + i]     = na[i].x;
            As[(2 * c + 1) * AP + 3 * rg + i] = na[i].y;
        }
        __syncthreads();
    };

    for (int v = 0; v < Lc - 1; ++v) {
        // Per-row (dt, output j) schedule: fwd t_s->t_{s+1} while v < fs,
        // then bwd t_s->t_{s-1} (state was reset to y0 at the boundary).
#pragma unroll
        for (int i = 0; i < 3; ++i) {
            if (v < fs_[i]) {
                const int s = t_[i] + v;
                dt_[i] = tss[s + 1] - tss[s];
                jj[i]  = s + 1;
            } else {
                const int s = t_[i] - (v - fs_[i]);
                dt_[i] = tss[s - 1] - tss[s];
                jj[i]  = s - 1;
            }
        }
        float2 k1[3], k2[3], k3[3], k4[3], na[3];
        evalf(k1);
#pragma unroll
        for (int i = 0; i < 3; ++i) {
            const float cdt = dt_[i] * (1.0f / 3.0f);
            na[i].x = fmaf(cdt, k1[i].x, y_[i].x);
            na[i].y = fmaf(cdt, k1[i].y, y_[i].y);
        }
        putArg(na);
        evalf(k2);
#pragma unroll
        for (int i = 0; i < 3; ++i) {
            na[i].x = y_[i].x + dt_[i] * (k2[i].x - (1.0f / 3.0f) * k1[i].x);
            na[i].y = y_[i].y + dt_[i] * (k2[i].y - (1.0f / 3.0f) * k1[i].y);
        }
        putArg(na);
        evalf(k3);
#pragma unroll
        for (int i = 0; i < 3; ++i) {
            na[i].x = y_[i].x + dt_[i] * (k1[i].x - k2[i].x + k3[i].x);
            na[i].y = y_[i].y + dt_[i] * (k1[i].y - k2[i].y + k3[i].y);
        }
        putArg(na);
        evalf(k4);
#pragma unroll
        for (int i = 0; i < 3; ++i) {
            y_[i].x += dt_[i] * (k1[i].x + 3.0f * (k2[i].x + k3[i].x) + k4[i].x) * 0.125f;
            y_[i].y += dt_[i] * (k1[i].y + 3.0f * (k2[i].y + k3[i].y) + k4[i].y) * 0.125f;
            float4 o; o.x = y0_[i].x; o.y = y_[i].x; o.z = y0_[i].y; o.w = y_[i].y;
            *(float4*)(out + ob_[i] + (long)jj[i] * (Hc * Ec * 2)) = o;
            if (v + 1 == fs_[i]) y_[i] = y0_[i];   // switch to backward sweep
            na[i] = y_[i];
        }
        putArg(na);
    }
}

extern "C" void kernel_launch(void* const* d_in, const int* in_sizes, int n_in,
                              void* d_out, int out_size, void* d_ws, size_t ws_size,
                              hipStream_t stream) {
    const float* x  = (const float*)d_in[0];
    const float* ts = (const float*)d_in[1];
    const float* W1 = (const float*)d_in[2];
    const float* b1 = (const float*)d_in[3];
    const float* W2 = (const float*)d_in[4];
    const float* b2 = (const float*)d_in[5];
    float* out = (float*)d_out;

    dim3 grid(256);    // 6144 row-slots / 24 per block
    dim3 block(256);
    ode_traj_kernel<<<grid, block, 0, stream>>>(x, ts, W1, b1, W2, b2, out);
}

// Round 3
// 695.930 us; speedup vs baseline: 4.0224x; 3.9315x over previous
//
#include <hip/hip_runtime.h>
#include <stdint.h>

#define Lc 96
#define Hc 8
#define Ec 64
#define EHc 128
#define AP 68            // A_pk pitch in dwords (16B-aligned rows, 2-way-only banks)
#define HP 132           // H_pk pitch in dwords
#define JS (Hc * Ec * 2) // out stride per j = 1024 floats

typedef __attribute__((ext_vector_type(8))) short short8;
typedef __attribute__((ext_vector_type(4))) float floatx4;

union Frag  { uint32_t u[4]; short8 v; };
union FragH { uint16_t h[8]; short8 v; };

// tanh(x) = 1 - 2/(e^{2x}+1)
__device__ __forceinline__ float fast_tanh(float x) {
    const float e = __builtin_amdgcn_exp2f(x * 2.8853900817779268f);
    return 1.0f - 2.0f * __builtin_amdgcn_rcpf(e + 1.0f);
}

// fp32 -> packed (hi bf16 in low16) | (lo bf16 in high16); hi truncated,
// lo = bf16(v - hi) so hi+lo carries ~16 mantissa bits.
__device__ __forceinline__ uint32_t pack_hl(float v) {
    const uint32_t uv = __float_as_uint(v);
    const float hf = __uint_as_float(uv & 0xffff0000u);
    const uint32_t lo = __float_as_uint(v - hf) >> 16;
    return (uv >> 16) | (lo << 16);
}

// Block = 4 waves x 64 = 256 threads; M = 16 rows (one trajectory slice).
// Wave w owns: L1 hidden cols [32w,32w+32) (2 col-tiles), L2 out cols [16w,16w+16).
// Weights are register-resident B-frags (bf16 hi/lo). Activations round-trip
// LDS as packed hi|lo u32; A-operand frags read as ds_read_b128 + bit unpack.
__global__ __launch_bounds__(256, 2)
void ode_mfma_kernel(const float* __restrict__ x, const float* __restrict__ ts,
                     const float* __restrict__ W1, const float* __restrict__ b1,
                     const float* __restrict__ W2, const float* __restrict__ b2,
                     float* __restrict__ out)
{
    __shared__ uint32_t A_pk[16 * AP];   // arg,   [row][e]   packed hi|lo
    __shared__ uint32_t H_pk[16 * HP];   // hidden,[row][n]   packed hi|lo
    __shared__ float    tss[Lc];

    const int tid  = threadIdx.x;
    const int w    = tid >> 6;      // wave 0..3
    const int lane = tid & 63;
    const int g    = lane >> 4;     // quad 0..3
    const int c    = lane & 15;

    if (tid < Lc) tss[tid] = ts[tid];

    // ---- register-resident weight B-fragments: B[k = ks*32 + g*8 + j][n] ----
    short8 w1h[2][2], w1l[2][2];           // [ct][ks]
#pragma unroll
    for (int ct = 0; ct < 2; ++ct)
#pragma unroll
        for (int ks = 0; ks < 2; ++ks) {
            FragH fh, fl;
#pragma unroll
            for (int j = 0; j < 8; ++j) {
                const int k = ks * 32 + g * 8 + j;
                const int n = 32 * w + 16 * ct + c;
                const float v = W1[k * EHc + n];
                const uint32_t uv = __float_as_uint(v);
                const float hf = __uint_as_float(uv & 0xffff0000u);
                fh.h[j] = (uint16_t)(uv >> 16);
                fl.h[j] = (uint16_t)(__float_as_uint(v - hf) >> 16);
            }
            w1h[ct][ks] = fh.v; w1l[ct][ks] = fl.v;
        }
    short8 w2h[4], w2l[4];                 // [ks]
#pragma unroll
    for (int ks = 0; ks < 4; ++ks) {
        FragH fh, fl;
#pragma unroll
        for (int j = 0; j < 8; ++j) {
            const int k = ks * 32 + g * 8 + j;
            const int n = 16 * w + c;
            const float v = W2[k * Ec + n];
            const uint32_t uv = __float_as_uint(v);
            const float hf = __uint_as_float(uv & 0xffff0000u);
            fh.h[j] = (uint16_t)(uv >> 16);
            fl.h[j] = (uint16_t)(__float_as_uint(v - hf) >> 16);
        }
        w2h[ks] = fh.v; w2l[ks] = fl.v;
    }

    const float b1v0 = b1[32 * w + c];
    const float b1v1 = b1[32 * w + 16 + c];
    const float b2v  = b2[16 * w + c];

    // ---- per-lane state: C/D layout, rows r = g*4+reg, col e = 16w+c ----
    const int t_blk = (blockIdx.x * 16) >> 6;    // uniform: 16 divides 64
    const int fs    = (Lc - 1) - t_blk;          // forward step count
    const int col   = 16 * w + c;

    float y0_[4], y_[4];
    float* outp[4];
#pragma unroll
    for (int reg = 0; reg < 4; ++reg) {
        const int rs = blockIdx.x * 16 + g * 4 + reg;   // global row-slot
        const int bidx = (rs & 63) >> 3;
        const int hh   = rs & 7;
        const float v0 = x[((bidx * Lc + t_blk) * Hc + hh) * Ec + col];
        y0_[reg] = v0; y_[reg] = v0;
        outp[reg] = out + (size_t)(bidx * Lc + t_blk) * (Lc * JS) + hh * (Ec * 2) + col * 2;
        float2 o; o.x = v0; o.y = v0;                   // j = t: (y0, y0)
        *(float2*)(outp[reg] + (size_t)t_blk * JS) = o;
        A_pk[(g * 4 + reg) * AP + col] = pack_hl(v0);   // initial argument
    }
    __syncthreads();

    // f(A_pk) -> this lane's 4 output values (C/D layout). Entry: A_pk synced.
    // One internal barrier (H handoff). Caller barriers after next A_pk write.
    auto evalf = [&]() -> floatx4 {
        Frag ah[2], al[2];
#pragma unroll
        for (int ks = 0; ks < 2; ++ks) {
            const uint32_t* p = A_pk + c * AP + ks * 32 + g * 8;
            const uint4 d0 = *(const uint4*)p;
            const uint4 d1 = *(const uint4*)(p + 4);
            ah[ks].u[0] = (d0.x & 0xffffu) | (d0.y << 16);
            ah[ks].u[1] = (d0.z & 0xffffu) | (d0.w << 16);
            ah[ks].u[2] = (d1.x & 0xffffu) | (d1.y << 16);
            ah[ks].u[3] = (d1.z & 0xffffu) | (d1.w << 16);
            al[ks].u[0] = (d0.x >> 16) | (d0.y & 0xffff0000u);
            al[ks].u[1] = (d0.z >> 16) | (d0.w & 0xffff0000u);
            al[ks].u[2] = (d1.x >> 16) | (d1.y & 0xffff0000u);
            al[ks].u[3] = (d1.z >> 16) | (d1.w & 0xffff0000u);
        }
        floatx4 p0 = {b1v0, b1v0, b1v0, b1v0};
        floatx4 p1 = {b1v1, b1v1, b1v1, b1v1};
#pragma unroll
        for (int ks = 0; ks < 2; ++ks) {
            p0 = __builtin_amdgcn_mfma_f32_16x16x32_bf16(ah[ks].v, w1h[0][ks], p0, 0, 0, 0);
            p0 = __builtin_amdgcn_mfma_f32_16x16x32_bf16(ah[ks].v, w1l[0][ks], p0, 0, 0, 0);
            p0 = __builtin_amdgcn_mfma_f32_16x16x32_bf16(al[ks].v, w1h[0][ks], p0, 0, 0, 0);
            p1 = __builtin_amdgcn_mfma_f32_16x16x32_bf16(ah[ks].v, w1h[1][ks], p1, 0, 0, 0);
            p1 = __builtin_amdgcn_mfma_f32_16x16x32_bf16(ah[ks].v, w1l[1][ks], p1, 0, 0, 0);
            p1 = __builtin_amdgcn_mfma_f32_16x16x32_bf16(al[ks].v, w1h[1][ks], p1, 0, 0, 0);
        }
#pragma unroll
        for (int reg = 0; reg < 4; ++reg) {
            const int r = g * 4 + reg;
            H_pk[r * HP + 32 * w + c]      = pack_hl(fast_tanh(p0[reg]));
            H_pk[r * HP + 32 * w + 16 + c] = pack_hl(fast_tanh(p1[reg]));
        }
        __syncthreads();
        floatx4 o = {b2v, b2v, b2v, b2v};
#pragma unroll
        for (int ks = 0; ks < 4; ++ks) {
            const uint32_t* p = H_pk + c * HP + ks * 32 + g * 8;
            const uint4 d0 = *(const uint4*)p;
            const uint4 d1 = *(const uint4*)(p + 4);
            Frag hh_, hl_;
            hh_.u[0] = (d0.x & 0xffffu) | (d0.y << 16);
            hh_.u[1] = (d0.z & 0xffffu) | (d0.w << 16);
            hh_.u[2] = (d1.x & 0xffffu) | (d1.y << 16);
            hh_.u[3] = (d1.z & 0xffffu) | (d1.w << 16);
            hl_.u[0] = (d0.x >> 16) | (d0.y & 0xffff0000u);
            hl_.u[1] = (d0.z >> 16) | (d0.w & 0xffff0000u);
            hl_.u[2] = (d1.x >> 16) | (d1.y & 0xffff0000u);
            hl_.u[3] = (d1.z >> 16) | (d1.w & 0xffff0000u);
            o = __builtin_amdgcn_mfma_f32_16x16x32_bf16(hh_.v, w2h[ks], o, 0, 0, 0);
            o = __builtin_amdgcn_mfma_f32_16x16x32_bf16(hh_.v, w2l[ks], o, 0, 0, 0);
            o = __builtin_amdgcn_mfma_f32_16x16x32_bf16(hl_.v, w2h[ks], o, 0, 0, 0);
        }
        return o;
    };

    auto putA = [&](const float* a4) {
#pragma unroll
        for (int reg = 0; reg < 4; ++reg)
            A_pk[(g * 4 + reg) * AP + col] = pack_hl(a4[reg]);
        __syncthreads();
    };

    for (int v = 0; v < Lc - 1; ++v) {
        float dt; int jo;
        if (v < fs) { const int s = t_blk + v;        dt = tss[s + 1] - tss[s]; jo = s + 1; }
        else        { const int s = t_blk - (v - fs); dt = tss[s - 1] - tss[s]; jo = s - 1; }

        float a[4];
        const floatx4 k1 = evalf();
#pragma unroll
        for (int reg = 0; reg < 4; ++reg)
            a[reg] = fmaf(dt * (1.0f / 3.0f), k1[reg], y_[reg]);
        putA(a);
        const floatx4 k2 = evalf();
#pragma unroll
        for (int reg = 0; reg < 4; ++reg)
            a[reg] = y_[reg] + dt * (k2[reg] - (1.0f / 3.0f) * k1[reg]);
        putA(a);
        const floatx4 k3 = evalf();
#pragma unroll
        for (int reg = 0; reg < 4; ++reg)
            a[reg] = y_[reg] + dt * (k1[reg] - k2[reg] + k3[reg]);
        putA(a);
        const floatx4 k4 = evalf();
#pragma unroll
        for (int reg = 0; reg < 4; ++reg) {
            y_[reg] += dt * (k1[reg] + 3.0f * (k2[reg] + k3[reg]) + k4[reg]) * 0.125f;
            float2 o; o.x = y0_[reg]; o.y = y_[reg];
            *(float2*)(outp[reg] + (size_t)jo * JS) = o;
        }
        if (v + 1 == fs) {
#pragma unroll
            for (int reg = 0; reg < 4; ++reg) y_[reg] = y0_[reg];  // start bwd sweep
        }
#pragma unroll
        for (int reg = 0; reg < 4; ++reg) a[reg] = y_[reg];
        putA(a);
    }
}

extern "C" void kernel_launch(void* const* d_in, const int* in_sizes, int n_in,
                              void* d_out, int out_size, void* d_ws, size_t ws_size,
                              hipStream_t stream) {
    const float* x  = (const float*)d_in[0];
    const float* ts = (const float*)d_in[1];
    const float* W1 = (const float*)d_in[2];
    const float* b1 = (const float*)d_in[3];
    const float* W2 = (const float*)d_in[4];
    const float* b2 = (const float*)d_in[5];
    float* out = (float*)d_out;

    dim3 grid(6144 / 16);   // 384 blocks x 16 rows = 96 traj x 64 rows
    dim3 block(256);
    ode_mfma_kernel<<<grid, block, 0, stream>>>(x, ts, W1, b1, W2, b2, out);
}